// Round 1
// baseline (150.289 us; speedup 1.0000x reference)
//
#include <hip/hip_runtime.h>

#define LSEQ 384
#define DIM 256
#define H 32
#define ODIM 128
#define EPSV 1e-5f
#define JT 192  // j-tile width for z kernel (2 tiles x 192 = 384)

#define FMA4(A, S, T)                                        \
  do {                                                       \
    (A).x += (S) * (T).x; (A).y += (S) * (T).y;              \
    (A).z += (S) * (T).z; (A).w += (S) * (T).w;              \
  } while (0)

// ---------------------------------------------------------------------------
// Kernel 1 (fused): LayerNorm + a/b projections + t[i,o,d] = sum_c a[i,c]*Wo[o,c*32+d]
// grid = 384: block = (i-pair, o-half). LN+proj duplicated across the o-half
// pair (cheap); t-stage per block covers 64 of 128 o values -> per-block Wo
// stream halved to 256KB and block parallelism doubled vs previous version.
// ---------------------------------------------------------------------------
__global__ __launch_bounds__(256) void ln_ab_t_kernel(
    const float* __restrict__ x, const float* __restrict__ gamma,
    const float* __restrict__ beta, const float* __restrict__ Wa,
    const float* __restrict__ Wb, const float* __restrict__ Wo,
    float* __restrict__ bT_g, float* __restrict__ t_g) {
  const int ipair = blockIdx.x >> 1;
  const int ohalf = blockIdx.x & 1;
  const int i0 = ipair * 2;
  const int tid = threadIdx.x;
  __shared__ float xn_s[2][DIM];
  __shared__ float psum[2][256];
  __shared__ float red_s[2][4];
  __shared__ float mu_s[2], rs_s[2];
  __shared__ float a_s[2][H];

  const float xv0 = x[i0 * DIM + tid];
  const float xv1 = x[(i0 + 1) * DIM + tid];
  const int wave = tid >> 6, lane = tid & 63;

  // means (both rows through one shuffle ladder)
  float s0 = xv0, s1 = xv1;
#pragma unroll
  for (int off = 32; off > 0; off >>= 1) {
    s0 += __shfl_down(s0, off, 64);
    s1 += __shfl_down(s1, off, 64);
  }
  if (lane == 0) { red_s[0][wave] = s0; red_s[1][wave] = s1; }
  __syncthreads();
  if (tid < 2)
    mu_s[tid] = (red_s[tid][0] + red_s[tid][1] + red_s[tid][2] + red_s[tid][3]) * (1.0f / DIM);
  __syncthreads();
  const float dv0 = xv0 - mu_s[0];
  const float dv1 = xv1 - mu_s[1];

  // variances
  float q0 = dv0 * dv0, q1 = dv1 * dv1;
#pragma unroll
  for (int off = 32; off > 0; off >>= 1) {
    q0 += __shfl_down(q0, off, 64);
    q1 += __shfl_down(q1, off, 64);
  }
  if (lane == 0) { red_s[0][wave] = q0; red_s[1][wave] = q1; }
  __syncthreads();
  if (tid < 2)
    rs_s[tid] = rsqrtf((red_s[tid][0] + red_s[tid][1] + red_s[tid][2] + red_s[tid][3]) * (1.0f / DIM) + EPSV);
  __syncthreads();

  const float g = gamma[tid], bb = beta[tid];
  xn_s[0][tid] = dv0 * rs_s[0] * g + bb;
  xn_s[1][tid] = dv1 * rs_s[1] * g + bb;
  __syncthreads();

  // projections: 64 outputs (32 a, 32 b) x 4 k-parts; both rows per thread.
  {
    const int out = tid >> 2;     // 0..63
    const int part = tid & 3;     // 0..3
    const int which = out >> 5;   // 0 = a, 1 = b
    const int c = out & 31;
    const float* W = which ? Wb : Wa;
    const float4* Wrow = (const float4*)(W + c * DIM);
    const float4* xn40 = (const float4*)&xn_s[0][0];
    const float4* xn41 = (const float4*)&xn_s[1][0];
    float acc0 = 0.f, acc1 = 0.f;
#pragma unroll
    for (int k = part * 16; k < part * 16 + 16; ++k) {
      const float4 w = Wrow[k];
      const float4 x0 = xn40[k];
      const float4 x1 = xn41[k];
      acc0 += w.x * x0.x + w.y * x0.y + w.z * x0.z + w.w * x0.w;
      acc1 += w.x * x1.x + w.y * x1.y + w.z * x1.z + w.w * x1.w;
    }
    psum[0][tid] = acc0;
    psum[1][tid] = acc1;
  }
  __syncthreads();
  if (tid < 128) {
    const int row = tid >> 6;     // which i
    const int out = tid & 63;
    const float v = psum[row][out * 4] + psum[row][out * 4 + 1] +
                    psum[row][out * 4 + 2] + psum[row][out * 4 + 3];
    const int wh = out >> 5, cc = out & 31;
    if (wh == 0) a_s[row][cc] = v;
    else if (ohalf == 0) bT_g[cc * LSEQ + i0 + row] = v;  // write bT once per i-pair
  }
  __syncthreads();

  // t half-stage: this block covers o in [ohalf*64, ohalf*64+64).
  // thread = (o_local, d-quarter of 8); both rows.
  const int ol = tid >> 2;          // 0..63
  const int dq = tid & 3;           // 0..3 -> d range [dq*8, dq*8+8) = 2 float4
  const int o = ohalf * 64 + ol;

  float4 acc00 = make_float4(0.f, 0.f, 0.f, 0.f);
  float4 acc01 = make_float4(0.f, 0.f, 0.f, 0.f);
  float4 acc10 = make_float4(0.f, 0.f, 0.f, 0.f);
  float4 acc11 = make_float4(0.f, 0.f, 0.f, 0.f);

  const float4* W4 = (const float4*)Wo;
#pragma unroll 8
  for (int c = 0; c < H; ++c) {
    const int base = o * 256 + c * 8 + dq * 2;
    const float4 w0 = W4[base];
    const float4 w1 = W4[base + 1];
    const float a0 = a_s[0][c];
    const float a1 = a_s[1][c];
    FMA4(acc00, a0, w0); FMA4(acc01, a0, w1);
    FMA4(acc10, a1, w0); FMA4(acc11, a1, w1);
  }

  float4* t4 = (float4*)t_g;
  const int b40 = i0 * (ODIM * H / 4) + o * 8 + dq * 2;
  const int b41 = (i0 + 1) * (ODIM * H / 4) + o * 8 + dq * 2;
  t4[b40] = acc00; t4[b40 + 1] = acc01;
  t4[b41] = acc10; t4[b41 + 1] = acc11;
}

// ---------------------------------------------------------------------------
// Kernel 2: z[i, j, o] = sum_d t[i,o,d] * b[j,d] + bo[o]
// Block = (i, j-tile of 192). grid = 384 x 2 = 768 blocks = exactly 3/CU
// (LDS 41.5KB, launch_bounds(256,3)). 256 threads = 16 (o-pair-of-quads) x
// 16 (j-groups of 12). Thread: 12j x 8o register tile; 5 ds_read_b128 feed
// 96 FMAs per d-step (19:1); conflict-free LDS; float4 coalesced stores.
// ---------------------------------------------------------------------------
__global__ __launch_bounds__(256, 3) void z_kernel(
    const float* __restrict__ t_g, const float* __restrict__ bT_g,
    const float* __restrict__ bo, float* __restrict__ z) {
  const int i = blockIdx.x;       // 0..383
  const int jt = blockIdx.y;      // 0..1
  const int tid = threadIdx.x;
  const int ot = tid & 15;        // o-quads 4*ot and 64+4*ot
  const int jg = tid >> 4;        // 0..15 (j-group of 12)

  __shared__ float tt[H][132];    // [d][o], padded row stride
  __shared__ float bt[H][JT];     // [d][j within tile]

  // stage t[i] -> tt (transpose to [d][o])
  const float4* t4 = (const float4*)(t_g + i * (ODIM * H));
#pragma unroll
  for (int k = 0; k < 4; ++k) {
    const int f = tid + k * 256;
    const float4 v = t4[f];
    const int o = f >> 3;
    const int d = (f & 7) * 4;
    tt[d][o] = v.x; tt[d + 1][o] = v.y; tt[d + 2][o] = v.z; tt[d + 3][o] = v.w;
  }
  // stage bT tile -> bt: thread owns row d = tid>>3, cols (tid&7) + 8k (div-free)
  {
    const int d = tid >> 3;       // 0..31
    const int c0 = tid & 7;       // float4 column base
    const float* src = bT_g + d * LSEQ + jt * JT;
#pragma unroll
    for (int k = 0; k < 6; ++k) {
      const int c4 = c0 + k * 8;  // 0..47
      const float4 v = *(const float4*)(src + c4 * 4);
      *(float4*)&bt[d][c4 * 4] = v;
    }
  }
  __syncthreads();

  const float4 bo0 = ((const float4*)bo)[ot];
  const float4 bo1 = ((const float4*)bo)[16 + ot];
  float4 acc0[12], acc1[12];
#pragma unroll
  for (int jj = 0; jj < 12; ++jj) { acc0[jj] = bo0; acc1[jj] = bo1; }

#pragma unroll 8
  for (int d = 0; d < H; ++d) {
    const float4 tv0 = *(const float4*)&tt[d][ot * 4];
    const float4 tv1 = *(const float4*)&tt[d][64 + ot * 4];
    const float4 b0 = *(const float4*)&bt[d][jg * 12];
    const float4 b1 = *(const float4*)&bt[d][jg * 12 + 4];
    const float4 b2 = *(const float4*)&bt[d][jg * 12 + 8];
    FMA4(acc0[0], b0.x, tv0);  FMA4(acc1[0], b0.x, tv1);
    FMA4(acc0[1], b0.y, tv0);  FMA4(acc1[1], b0.y, tv1);
    FMA4(acc0[2], b0.z, tv0);  FMA4(acc1[2], b0.z, tv1);
    FMA4(acc0[3], b0.w, tv0);  FMA4(acc1[3], b0.w, tv1);
    FMA4(acc0[4], b1.x, tv0);  FMA4(acc1[4], b1.x, tv1);
    FMA4(acc0[5], b1.y, tv0);  FMA4(acc1[5], b1.y, tv1);
    FMA4(acc0[6], b1.z, tv0);  FMA4(acc1[6], b1.z, tv1);
    FMA4(acc0[7], b1.w, tv0);  FMA4(acc1[7], b1.w, tv1);
    FMA4(acc0[8], b2.x, tv0);  FMA4(acc1[8], b2.x, tv1);
    FMA4(acc0[9], b2.y, tv0);  FMA4(acc1[9], b2.y, tv1);
    FMA4(acc0[10], b2.z, tv0); FMA4(acc1[10], b2.z, tv1);
    FMA4(acc0[11], b2.w, tv0); FMA4(acc1[11], b2.w, tv1);
  }

  float4* z4 = (float4*)z;
  const int jbase = jt * JT + jg * 12;
#pragma unroll
  for (int jj = 0; jj < 12; ++jj) {
    const size_t row = (size_t)(i * LSEQ + jbase + jj) * 32;
    z4[row + ot] = acc0[jj];
    z4[row + 16 + ot] = acc1[jj];
  }
}

// ---------------------------------------------------------------------------
extern "C" void kernel_launch(void* const* d_in, const int* in_sizes, int n_in,
                              void* d_out, int out_size, void* d_ws, size_t ws_size,
                              hipStream_t stream) {
  const float* x     = (const float*)d_in[0];
  const float* gamma = (const float*)d_in[1];
  const float* beta  = (const float*)d_in[2];
  const float* Wa    = (const float*)d_in[3];
  const float* Wb    = (const float*)d_in[4];
  const float* Wo    = (const float*)d_in[5];
  const float* bo    = (const float*)d_in[6];
  float* z = (float*)d_out;

  float* ws   = (float*)d_ws;
  float* bT_g = ws;                       // 32*384
  float* t_g  = ws + LSEQ * H;            // 384*128*32 floats

  hipLaunchKernelGGL(ln_ab_t_kernel, dim3(LSEQ), dim3(256), 0, stream,
                     x, gamma, beta, Wa, Wb, Wo, bT_g, t_g);
  hipLaunchKernelGGL(z_kernel, dim3(LSEQ, LSEQ / JT), dim3(256), 0, stream,
                     t_g, bT_g, bo, z);
}

// Round 2
// 120.896 us; speedup vs baseline: 1.2431x; 1.2431x over previous
//
#include <hip/hip_runtime.h>

#define LSEQ 384
#define DIM 256
#define H 32
#define ODIM 128
#define EPSV 1e-5f

#define FMA4(A, S, T)                                        \
  do {                                                       \
    (A).x += (S) * (T).x; (A).y += (S) * (T).y;              \
    (A).z += (S) * (T).z; (A).w += (S) * (T).w;              \
  } while (0)

// ---------------------------------------------------------------------------
// Kernel 1 (fused): LayerNorm + a/b projections + t[i,d,o] = sum_c a[i,c]*Wo[o,c*32+d]
// grid = 384: block = (i-pair, o-half). LN+proj duplicated across the o-half
// pair (cheap); t-stage per block covers 64 of 128 o values.
// t is written TRANSPOSED ([i][d][o]) so kernel 2 can stage it into LDS with
// a linear float4 copy (no scatter, no padding). Stores are 4x64B segments
// per wave-instruction - coalesced at the 64B granule.
// ---------------------------------------------------------------------------
__global__ __launch_bounds__(256) void ln_ab_t_kernel(
    const float* __restrict__ x, const float* __restrict__ gamma,
    const float* __restrict__ beta, const float* __restrict__ Wa,
    const float* __restrict__ Wb, const float* __restrict__ Wo,
    float* __restrict__ bT_g, float* __restrict__ t_g) {
  const int ipair = blockIdx.x >> 1;
  const int ohalf = blockIdx.x & 1;
  const int i0 = ipair * 2;
  const int tid = threadIdx.x;
  __shared__ float xn_s[2][DIM];
  __shared__ float psum[2][256];
  __shared__ float red_s[2][4];
  __shared__ float mu_s[2], rs_s[2];
  __shared__ float a_s[2][H];

  const float xv0 = x[i0 * DIM + tid];
  const float xv1 = x[(i0 + 1) * DIM + tid];
  const int wave = tid >> 6, lane = tid & 63;

  // means (both rows through one shuffle ladder)
  float s0 = xv0, s1 = xv1;
#pragma unroll
  for (int off = 32; off > 0; off >>= 1) {
    s0 += __shfl_down(s0, off, 64);
    s1 += __shfl_down(s1, off, 64);
  }
  if (lane == 0) { red_s[0][wave] = s0; red_s[1][wave] = s1; }
  __syncthreads();
  if (tid < 2)
    mu_s[tid] = (red_s[tid][0] + red_s[tid][1] + red_s[tid][2] + red_s[tid][3]) * (1.0f / DIM);
  __syncthreads();
  const float dv0 = xv0 - mu_s[0];
  const float dv1 = xv1 - mu_s[1];

  // variances
  float q0 = dv0 * dv0, q1 = dv1 * dv1;
#pragma unroll
  for (int off = 32; off > 0; off >>= 1) {
    q0 += __shfl_down(q0, off, 64);
    q1 += __shfl_down(q1, off, 64);
  }
  if (lane == 0) { red_s[0][wave] = q0; red_s[1][wave] = q1; }
  __syncthreads();
  if (tid < 2)
    rs_s[tid] = rsqrtf((red_s[tid][0] + red_s[tid][1] + red_s[tid][2] + red_s[tid][3]) * (1.0f / DIM) + EPSV);
  __syncthreads();

  const float g = gamma[tid], bb = beta[tid];
  xn_s[0][tid] = dv0 * rs_s[0] * g + bb;
  xn_s[1][tid] = dv1 * rs_s[1] * g + bb;
  __syncthreads();

  // projections: 64 outputs (32 a, 32 b) x 4 k-parts; both rows per thread.
  {
    const int out = tid >> 2;     // 0..63
    const int part = tid & 3;     // 0..3
    const int which = out >> 5;   // 0 = a, 1 = b
    const int c = out & 31;
    const float* W = which ? Wb : Wa;
    const float4* Wrow = (const float4*)(W + c * DIM);
    const float4* xn40 = (const float4*)&xn_s[0][0];
    const float4* xn41 = (const float4*)&xn_s[1][0];
    float acc0 = 0.f, acc1 = 0.f;
#pragma unroll
    for (int k = part * 16; k < part * 16 + 16; ++k) {
      const float4 w = Wrow[k];
      const float4 x0 = xn40[k];
      const float4 x1 = xn41[k];
      acc0 += w.x * x0.x + w.y * x0.y + w.z * x0.z + w.w * x0.w;
      acc1 += w.x * x1.x + w.y * x1.y + w.z * x1.z + w.w * x1.w;
    }
    psum[0][tid] = acc0;
    psum[1][tid] = acc1;
  }
  __syncthreads();
  if (tid < 128) {
    const int row = tid >> 6;     // which i
    const int out = tid & 63;
    const float v = psum[row][out * 4] + psum[row][out * 4 + 1] +
                    psum[row][out * 4 + 2] + psum[row][out * 4 + 3];
    const int wh = out >> 5, cc = out & 31;
    if (wh == 0) a_s[row][cc] = v;
    else if (ohalf == 0) bT_g[cc * LSEQ + i0 + row] = v;  // write bT once per i-pair
  }
  __syncthreads();

  // t half-stage: this block covers o in [ohalf*64, ohalf*64+64).
  // thread = (o_local, d-quarter of 8); both rows.
  const int ol = tid >> 2;          // 0..63
  const int dq = tid & 3;           // 0..3 -> d range [dq*8, dq*8+8)
  const int o = ohalf * 64 + ol;

  float4 acc00 = make_float4(0.f, 0.f, 0.f, 0.f);
  float4 acc01 = make_float4(0.f, 0.f, 0.f, 0.f);
  float4 acc10 = make_float4(0.f, 0.f, 0.f, 0.f);
  float4 acc11 = make_float4(0.f, 0.f, 0.f, 0.f);

  const float4* W4 = (const float4*)Wo;
#pragma unroll 8
  for (int c = 0; c < H; ++c) {
    const int base = o * 256 + c * 8 + dq * 2;
    const float4 w0 = W4[base];
    const float4 w1 = W4[base + 1];
    const float a0 = a_s[0][c];
    const float a1 = a_s[1][c];
    FMA4(acc00, a0, w0); FMA4(acc01, a0, w1);
    FMA4(acc10, a1, w0); FMA4(acc11, a1, w1);
  }

  // store transposed: t_g[i][d][o]
  float* tp0 = t_g + i0 * (H * ODIM) + o;
  float* tp1 = tp0 + H * ODIM;
  const int d0 = dq * 8;
  tp0[(d0 + 0) * ODIM] = acc00.x; tp0[(d0 + 1) * ODIM] = acc00.y;
  tp0[(d0 + 2) * ODIM] = acc00.z; tp0[(d0 + 3) * ODIM] = acc00.w;
  tp0[(d0 + 4) * ODIM] = acc01.x; tp0[(d0 + 5) * ODIM] = acc01.y;
  tp0[(d0 + 6) * ODIM] = acc01.z; tp0[(d0 + 7) * ODIM] = acc01.w;
  tp1[(d0 + 0) * ODIM] = acc10.x; tp1[(d0 + 1) * ODIM] = acc10.y;
  tp1[(d0 + 2) * ODIM] = acc10.z; tp1[(d0 + 3) * ODIM] = acc10.w;
  tp1[(d0 + 4) * ODIM] = acc11.x; tp1[(d0 + 5) * ODIM] = acc11.y;
  tp1[(d0 + 6) * ODIM] = acc11.z; tp1[(d0 + 7) * ODIM] = acc11.w;
}

// ---------------------------------------------------------------------------
// Kernel 2: z[i, j, o] = sum_d t[i,d,o] * b[j,d] + bo[o]
// Block = (i, j-tile of 128), grid 384x3. 256 threads = 16 (o-pair-of-quads)
// x 16 (j-groups of 8). Thread: 8j x 8o register tile (64 acc floats -> no
// spill, VGPR ~100). t tile stages as a LINEAR float4 copy (t_g is [i][d][o]).
// LDS = exactly 32KB -> 5 blocks/CU. tt stride 128: tv reads are a 2-way
// bank alias (free); bt reads broadcast across 4 addresses (conflict-free).
// ---------------------------------------------------------------------------
__global__ __launch_bounds__(256) void z_kernel(
    const float* __restrict__ t_g, const float* __restrict__ bT_g,
    const float* __restrict__ bo, float* __restrict__ z) {
  const int i = blockIdx.x;       // 0..383
  const int jt = blockIdx.y;      // 0..2
  const int tid = threadIdx.x;
  const int ot = tid & 15;        // o-quads 4*ot and 64+4*ot
  const int jg = tid >> 4;        // 0..15 (j-group of 8)

  __shared__ float tt[H][128];    // [d][o] - matches t_g layout, no transpose
  __shared__ float bt[H][128];    // [d][j within tile]

  // stage t[i] -> tt: pure linear copy, 4 float4 per thread
  const float4* t4 = (const float4*)(t_g + i * (ODIM * H));
  float4* ttl = (float4*)&tt[0][0];
#pragma unroll
  for (int k = 0; k < 4; ++k) ttl[tid + k * 256] = t4[tid + k * 256];

  // stage bT tile -> bt
#pragma unroll
  for (int k = 0; k < 4; ++k) {
    const int idx4 = tid + k * 256;
    const int d = idx4 >> 5, c4 = idx4 & 31;
    const float4 v = *(const float4*)(bT_g + d * LSEQ + jt * 128 + c4 * 4);
    *(float4*)&bt[d][c4 * 4] = v;
  }
  __syncthreads();

  const float4 bo0 = ((const float4*)bo)[ot];
  const float4 bo1 = ((const float4*)bo)[16 + ot];
  float4 acc0[8], acc1[8];
#pragma unroll
  for (int jj = 0; jj < 8; ++jj) { acc0[jj] = bo0; acc1[jj] = bo1; }

#pragma unroll
  for (int d = 0; d < H; ++d) {
    const float4 tv0 = *(const float4*)&tt[d][ot * 4];
    const float4 tv1 = *(const float4*)&tt[d][64 + ot * 4];
    const float4 b0 = *(const float4*)&bt[d][jg * 8];
    const float4 b1 = *(const float4*)&bt[d][jg * 8 + 4];
    FMA4(acc0[0], b0.x, tv0); FMA4(acc1[0], b0.x, tv1);
    FMA4(acc0[1], b0.y, tv0); FMA4(acc1[1], b0.y, tv1);
    FMA4(acc0[2], b0.z, tv0); FMA4(acc1[2], b0.z, tv1);
    FMA4(acc0[3], b0.w, tv0); FMA4(acc1[3], b0.w, tv1);
    FMA4(acc0[4], b1.x, tv0); FMA4(acc1[4], b1.x, tv1);
    FMA4(acc0[5], b1.y, tv0); FMA4(acc1[5], b1.y, tv1);
    FMA4(acc0[6], b1.z, tv0); FMA4(acc1[6], b1.z, tv1);
    FMA4(acc0[7], b1.w, tv0); FMA4(acc1[7], b1.w, tv1);
  }

  float4* z4 = (float4*)z;
  const int jbase = jt * 128 + jg * 8;
#pragma unroll
  for (int jj = 0; jj < 8; ++jj) {
    const size_t row = (size_t)(i * LSEQ + jbase + jj) * 32;
    z4[row + ot] = acc0[jj];
    z4[row + 16 + ot] = acc1[jj];
  }
}

// ---------------------------------------------------------------------------
extern "C" void kernel_launch(void* const* d_in, const int* in_sizes, int n_in,
                              void* d_out, int out_size, void* d_ws, size_t ws_size,
                              hipStream_t stream) {
  const float* x     = (const float*)d_in[0];
  const float* gamma = (const float*)d_in[1];
  const float* beta  = (const float*)d_in[2];
  const float* Wa    = (const float*)d_in[3];
  const float* Wb    = (const float*)d_in[4];
  const float* Wo    = (const float*)d_in[5];
  const float* bo    = (const float*)d_in[6];
  float* z = (float*)d_out;

  float* ws   = (float*)d_ws;
  float* bT_g = ws;                       // 32*384
  float* t_g  = ws + LSEQ * H;            // 384*32*128 floats, [i][d][o]

  hipLaunchKernelGGL(ln_ab_t_kernel, dim3(LSEQ), dim3(256), 0, stream,
                     x, gamma, beta, Wa, Wb, Wo, bT_g, t_g);
  hipLaunchKernelGGL(z_kernel, dim3(LSEQ, LSEQ / 128), dim3(256), 0, stream,
                     t_g, bT_g, bo, z);
}

// Round 3
// 119.901 us; speedup vs baseline: 1.2534x; 1.0083x over previous
//
#include <hip/hip_runtime.h>

#define LSEQ 384
#define DIM 256
#define H 32
#define ODIM 128
#define EPSV 1e-5f

#define FMA4(A, S, T)                                        \
  do {                                                       \
    (A).x += (S) * (T).x; (A).y += (S) * (T).y;              \
    (A).z += (S) * (T).z; (A).w += (S) * (T).w;              \
  } while (0)

// ---------------------------------------------------------------------------
// Kernel 1 (fused): LayerNorm + a/b projections + t[i,d,o] = sum_c a[i,c]*Wo[o,c*32+d]
// grid = 768: block = (i-pair, o-QUARTER) -> 3.0 blocks/CU (was 1.5).
// LN+proj duplicated across the 4 o-quarter blocks (cheap: ~32K MACs);
// per-block Wo stream halved to 128KB; aggregate Wo traffic unchanged.
// t written [i][d][o] so kernel 2 stages it with a linear float4 copy.
// ---------------------------------------------------------------------------
__global__ __launch_bounds__(256) void ln_ab_t_kernel(
    const float* __restrict__ x, const float* __restrict__ gamma,
    const float* __restrict__ beta, const float* __restrict__ Wa,
    const float* __restrict__ Wb, const float* __restrict__ Wo,
    float* __restrict__ bT_g, float* __restrict__ t_g) {
  const int ipair = blockIdx.x >> 2;
  const int oq = blockIdx.x & 3;
  const int i0 = ipair * 2;
  const int tid = threadIdx.x;
  __shared__ float xn_s[2][DIM];
  __shared__ float psum[2][256];
  __shared__ float red_s[2][4];
  __shared__ float mu_s[2], rs_s[2];
  __shared__ float a_s[2][H];

  const float xv0 = x[i0 * DIM + tid];
  const float xv1 = x[(i0 + 1) * DIM + tid];
  const int wave = tid >> 6, lane = tid & 63;

  // means (both rows through one shuffle ladder)
  float s0 = xv0, s1 = xv1;
#pragma unroll
  for (int off = 32; off > 0; off >>= 1) {
    s0 += __shfl_down(s0, off, 64);
    s1 += __shfl_down(s1, off, 64);
  }
  if (lane == 0) { red_s[0][wave] = s0; red_s[1][wave] = s1; }
  __syncthreads();
  if (tid < 2)
    mu_s[tid] = (red_s[tid][0] + red_s[tid][1] + red_s[tid][2] + red_s[tid][3]) * (1.0f / DIM);
  __syncthreads();
  const float dv0 = xv0 - mu_s[0];
  const float dv1 = xv1 - mu_s[1];

  // variances
  float q0 = dv0 * dv0, q1 = dv1 * dv1;
#pragma unroll
  for (int off = 32; off > 0; off >>= 1) {
    q0 += __shfl_down(q0, off, 64);
    q1 += __shfl_down(q1, off, 64);
  }
  if (lane == 0) { red_s[0][wave] = q0; red_s[1][wave] = q1; }
  __syncthreads();
  if (tid < 2)
    rs_s[tid] = rsqrtf((red_s[tid][0] + red_s[tid][1] + red_s[tid][2] + red_s[tid][3]) * (1.0f / DIM) + EPSV);
  __syncthreads();

  const float g = gamma[tid], bb = beta[tid];
  xn_s[0][tid] = dv0 * rs_s[0] * g + bb;
  xn_s[1][tid] = dv1 * rs_s[1] * g + bb;
  __syncthreads();

  // projections: 64 outputs (32 a, 32 b) x 4 k-parts; both rows per thread.
  {
    const int out = tid >> 2;     // 0..63
    const int part = tid & 3;     // 0..3
    const int which = out >> 5;   // 0 = a, 1 = b
    const int c = out & 31;
    const float* W = which ? Wb : Wa;
    const float4* Wrow = (const float4*)(W + c * DIM);
    const float4* xn40 = (const float4*)&xn_s[0][0];
    const float4* xn41 = (const float4*)&xn_s[1][0];
    float acc0 = 0.f, acc1 = 0.f;
#pragma unroll
    for (int k = part * 16; k < part * 16 + 16; ++k) {
      const float4 w = Wrow[k];
      const float4 x0 = xn40[k];
      const float4 x1 = xn41[k];
      acc0 += w.x * x0.x + w.y * x0.y + w.z * x0.z + w.w * x0.w;
      acc1 += w.x * x1.x + w.y * x1.y + w.z * x1.z + w.w * x1.w;
    }
    psum[0][tid] = acc0;
    psum[1][tid] = acc1;
  }
  __syncthreads();
  if (tid < 128) {
    const int row = tid >> 6;     // which i
    const int out = tid & 63;
    const float v = psum[row][out * 4] + psum[row][out * 4 + 1] +
                    psum[row][out * 4 + 2] + psum[row][out * 4 + 3];
    const int wh = out >> 5, cc = out & 31;
    if (wh == 0) a_s[row][cc] = v;
    else if (oq == 0) bT_g[cc * LSEQ + i0 + row] = v;  // write bT once per i-pair
  }
  __syncthreads();

  // t quarter-stage: this block covers o in [oq*32, oq*32+32).
  // thread = (o_local 0..31, d-eighth 0..7); one float4 of d per row.
  // Loads: lanes consecutive in de -> 8 consecutive float4 = 128B contiguous.
  const int ol = tid >> 3;          // 0..31
  const int de = tid & 7;           // 0..7 -> d range [de*4, de*4+4)
  const int o = oq * 32 + ol;

  float4 acc0 = make_float4(0.f, 0.f, 0.f, 0.f);
  float4 acc1 = make_float4(0.f, 0.f, 0.f, 0.f);

  const float4* W4 = (const float4*)Wo;
#pragma unroll 8
  for (int c = 0; c < H; ++c) {
    const float4 w = W4[o * 256 + c * 8 + de];
    const float a0 = a_s[0][c];
    const float a1 = a_s[1][c];
    FMA4(acc0, a0, w);
    FMA4(acc1, a1, w);
  }

  // store transposed: t_g[i][d][o]
  float* tp0 = t_g + i0 * (H * ODIM) + o;
  float* tp1 = tp0 + H * ODIM;
  const int d0 = de * 4;
  tp0[(d0 + 0) * ODIM] = acc0.x; tp0[(d0 + 1) * ODIM] = acc0.y;
  tp0[(d0 + 2) * ODIM] = acc0.z; tp0[(d0 + 3) * ODIM] = acc0.w;
  tp1[(d0 + 0) * ODIM] = acc1.x; tp1[(d0 + 1) * ODIM] = acc1.y;
  tp1[(d0 + 2) * ODIM] = acc1.z; tp1[(d0 + 3) * ODIM] = acc1.w;
}

// ---------------------------------------------------------------------------
// Kernel 2: z[i, j, o] = sum_d t[i,d,o] * b[j,d] + bo[o]
// Block = (i, j-tile of 128), grid 384x3 = 1152 blocks, all co-resident
// (LDS exactly 32KB -> 5 blocks/CU). 256 threads = 16 (o-pair-of-quads)
// x 16 (j-groups of 8). Thread: 8j x 8o register tile (64 acc floats, no
// spill). t tile stages as a LINEAR float4 copy (t_g is [i][d][o]).
// Write-bound: 75.5MB output @ ~6TB/s = 12.6us floor.
// ---------------------------------------------------------------------------
__global__ __launch_bounds__(256) void z_kernel(
    const float* __restrict__ t_g, const float* __restrict__ bT_g,
    const float* __restrict__ bo, float* __restrict__ z) {
  const int i = blockIdx.x;       // 0..383
  const int jt = blockIdx.y;      // 0..2
  const int tid = threadIdx.x;
  const int ot = tid & 15;        // o-quads 4*ot and 64+4*ot
  const int jg = tid >> 4;        // 0..15 (j-group of 8)

  __shared__ float tt[H][128];    // [d][o] - matches t_g layout, no transpose
  __shared__ float bt[H][128];    // [d][j within tile]

  // stage t[i] -> tt: pure linear copy, 4 float4 per thread
  const float4* t4 = (const float4*)(t_g + i * (ODIM * H));
  float4* ttl = (float4*)&tt[0][0];
#pragma unroll
  for (int k = 0; k < 4; ++k) ttl[tid + k * 256] = t4[tid + k * 256];

  // stage bT tile -> bt
#pragma unroll
  for (int k = 0; k < 4; ++k) {
    const int idx4 = tid + k * 256;
    const int d = idx4 >> 5, c4 = idx4 & 31;
    const float4 v = *(const float4*)(bT_g + d * LSEQ + jt * 128 + c4 * 4);
    *(float4*)&bt[d][c4 * 4] = v;
  }
  __syncthreads();

  const float4 bo0 = ((const float4*)bo)[ot];
  const float4 bo1 = ((const float4*)bo)[16 + ot];
  float4 acc0[8], acc1[8];
#pragma unroll
  for (int jj = 0; jj < 8; ++jj) { acc0[jj] = bo0; acc1[jj] = bo1; }

#pragma unroll
  for (int d = 0; d < H; ++d) {
    const float4 tv0 = *(const float4*)&tt[d][ot * 4];
    const float4 tv1 = *(const float4*)&tt[d][64 + ot * 4];
    const float4 b0 = *(const float4*)&bt[d][jg * 8];
    const float4 b1 = *(const float4*)&bt[d][jg * 8 + 4];
    FMA4(acc0[0], b0.x, tv0); FMA4(acc1[0], b0.x, tv1);
    FMA4(acc0[1], b0.y, tv0); FMA4(acc1[1], b0.y, tv1);
    FMA4(acc0[2], b0.z, tv0); FMA4(acc1[2], b0.z, tv1);
    FMA4(acc0[3], b0.w, tv0); FMA4(acc1[3], b0.w, tv1);
    FMA4(acc0[4], b1.x, tv0); FMA4(acc1[4], b1.x, tv1);
    FMA4(acc0[5], b1.y, tv0); FMA4(acc1[5], b1.y, tv1);
    FMA4(acc0[6], b1.z, tv0); FMA4(acc1[6], b1.z, tv1);
    FMA4(acc0[7], b1.w, tv0); FMA4(acc1[7], b1.w, tv1);
  }

  float4* z4 = (float4*)z;
  const int jbase = jt * 128 + jg * 8;
#pragma unroll
  for (int jj = 0; jj < 8; ++jj) {
    const size_t row = (size_t)(i * LSEQ + jbase + jj) * 32;
    z4[row + ot] = acc0[jj];
    z4[row + 16 + ot] = acc1[jj];
  }
}

// ---------------------------------------------------------------------------
extern "C" void kernel_launch(void* const* d_in, const int* in_sizes, int n_in,
                              void* d_out, int out_size, void* d_ws, size_t ws_size,
                              hipStream_t stream) {
  const float* x     = (const float*)d_in[0];
  const float* gamma = (const float*)d_in[1];
  const float* beta  = (const float*)d_in[2];
  const float* Wa    = (const float*)d_in[3];
  const float* Wb    = (const float*)d_in[4];
  const float* Wo    = (const float*)d_in[5];
  const float* bo    = (const float*)d_in[6];
  float* z = (float*)d_out;

  float* ws   = (float*)d_ws;
  float* bT_g = ws;                       // 32*384
  float* t_g  = ws + LSEQ * H;            // 384*32*128 floats, [i][d][o]

  hipLaunchKernelGGL(ln_ab_t_kernel, dim3(LSEQ * 2), dim3(256), 0, stream,
                     x, gamma, beta, Wa, Wb, Wo, bT_g, t_g);
  hipLaunchKernelGGL(z_kernel, dim3(LSEQ, LSEQ / 128), dim3(256), 0, stream,
                     t_g, bT_g, bo, z);
}